// Round 1
// baseline (545.238 us; speedup 1.0000x reference)
//
#include <hip/hip_runtime.h>
#include <math.h>

#define N_NODES 50000
#define IN_F 256
#define OUT_F 64

// ---------------- zero-init output ----------------
__global__ __launch_bounds__(256) void zero_kernel(float4* __restrict__ out, int n4) {
    int i = blockIdx.x * 256 + threadIdx.x;
    if (i < n4) out[i] = make_float4(0.f, 0.f, 0.f, 0.f);
}

// ---------------- dense projection: support = features @ W ----------------
// Block = 256 threads = 4 waves. Each wave handles 8 rows; lane = output col.
// W staged in LDS [k][col]; one ds_read_b32 of W feeds 8 FMAs (register-blocked
// over rows). Feature-row pointers are wave-uniform (readfirstlane) so the
// compiler can scalarize the feature loads into s_load.
__global__ __launch_bounds__(256) void gemm_kernel(const float* __restrict__ feat,
                                                   const float* __restrict__ W,
                                                   float* __restrict__ sup) {
    __shared__ float wl[IN_F * OUT_F];  // 64 KB
    for (int i = threadIdx.x; i < IN_F * OUT_F; i += 256) wl[i] = W[i];
    __syncthreads();

    const int col  = threadIdx.x & 63;
    const int warp = __builtin_amdgcn_readfirstlane(threadIdx.x >> 6);
    const int row0 = blockIdx.x * 32 + warp * 8;   // block covers 32 rows

    const float* frp[8];
#pragma unroll
    for (int r = 0; r < 8; ++r) {
        int row = row0 + r;
        row = row < N_NODES ? row : N_NODES - 1;   // clamp (reads dup'd, writes guarded)
        frp[r] = feat + (size_t)row * IN_F;
    }

    float acc[8] = {0.f, 0.f, 0.f, 0.f, 0.f, 0.f, 0.f, 0.f};
#pragma unroll 4
    for (int k = 0; k < IN_F; ++k) {
        float wv = wl[k * OUT_F + col];
#pragma unroll
        for (int r = 0; r < 8; ++r) acc[r] += frp[r][k] * wv;
    }

#pragma unroll
    for (int r = 0; r < 8; ++r) {
        int row = row0 + r;
        if (row < N_NODES) sup[(size_t)row * OUT_F + col] = acc[r];
    }
}

// ---------------- COO SpMM scatter: out[row] += w * support[col] ----------------
// One wave per edge, lane = output column. Gather is a coalesced 256B read
// (support fits in L2/L3); scatter is 64 consecutive fp32 atomics.
__global__ __launch_bounds__(256) void scatter_kernel(const float* __restrict__ sup,
                                                      const int* __restrict__ erow,
                                                      const int* __restrict__ ecol,
                                                      const float* __restrict__ ew,
                                                      float* __restrict__ out, int E) {
    int e = blockIdx.x * 4 + (threadIdx.x >> 6);
    if (e >= E) return;
    int lane = threadIdx.x & 63;
    int r = erow[e];
    int c = ecol[e];
    float w = ew[e];
    float v = sup[(size_t)c * OUT_F + lane] * w;
    atomicAdd(&out[(size_t)r * OUT_F + lane], v);
}

// ---------------- tanh epilogue (conditional on `active`) ----------------
__global__ __launch_bounds__(256) void tanh_kernel(float4* __restrict__ out,
                                                   const int* __restrict__ active, int n4) {
    int i = blockIdx.x * 256 + threadIdx.x;
    if (i >= n4) return;
    float4 v = out[i];
    if (*active) {
        v.x = tanhf(v.x);
        v.y = tanhf(v.y);
        v.z = tanhf(v.z);
        v.w = tanhf(v.w);
    }
    out[i] = v;
}

extern "C" void kernel_launch(void* const* d_in, const int* in_sizes, int n_in,
                              void* d_out, int out_size, void* d_ws, size_t ws_size,
                              hipStream_t stream) {
    const float* feat = (const float*)d_in[0];
    const float* W    = (const float*)d_in[1];
    const int*   erow = (const int*)d_in[2];
    const int*   ecol = (const int*)d_in[3];
    const float* ew   = (const float*)d_in[4];
    const int*   act  = (const int*)d_in[5];
    float* out = (float*)d_out;
    float* sup = (float*)d_ws;  // 50000*64*4 = 12.8 MB scratch

    const int E = in_sizes[2];
    const int n4 = (N_NODES * OUT_F) / 4;  // 800000 float4

    // zero output (harness poisons with 0xAA)
    zero_kernel<<<(n4 + 255) / 256, 256, 0, stream>>>((float4*)out, n4);

    // support = feat @ W
    gemm_kernel<<<(N_NODES + 31) / 32, 256, 0, stream>>>(feat, W, sup);

    // scatter-add messages
    scatter_kernel<<<(E + 3) / 4, 256, 0, stream>>>(sup, erow, ecol, ew, out, E);

    // tanh epilogue
    tanh_kernel<<<(n4 + 255) / 256, 256, 0, stream>>>((float4*)out, act, n4);
}